// Round 4
// baseline (313.448 us; speedup 1.0000x reference)
//
#include <hip/hip_runtime.h>
#include <cmath>

// Problem constants (from reference)
static constexpr int BERT   = 768;
static constexpr int HID    = 256;
static constexpr int NLAB   = 9;
static constexpr int NUFD   = 20;
static constexpr int NB     = 64;
static constexpr int NR     = 16;
static constexpr int NS     = 64;
static constexpr int PBD    = HID + NUFD;  // 276

typedef float v4f __attribute__((ext_vector_type(4)));

// Workspace layout (float offsets). Total ~806,976 floats = 3.23 MB.
static constexpr size_t WS_A      = 0;          // [1024][768] masked row-sums
static constexpr size_t WS_COLSUM = 786432;     // [768]
static constexpr size_t WS_SUMB   = 787200;     // [1]
static constexpr size_t WS_CNT    = 787264;     // [1024]
static constexpr size_t WS_TSUM   = 788288;     // [1024]
static constexpr size_t WS_PB     = 789312;     // [64][276] p_batch

__device__ __forceinline__ float selu_f(float x) {
    const float alpha = 1.6732632423543772848170429916717f;
    const float scale = 1.0507009873554804934193349852946f;
    return scale * (x > 0.0f ? x : alpha * (expf(x) - 1.0f));
}

// K0: colsum[d] = sum_h W_proj[d][h]; sumb = sum(b_proj);
// also zeroes A / cnt / tsum (ws is poisoned 0xAA before every launch and
// k1 now accumulates into them with atomicAdd).
__global__ __launch_bounds__(256) void k0_colsum(
    const float* __restrict__ W, const float* __restrict__ bp,
    float* __restrict__ colsum, float* __restrict__ sumb,
    float* __restrict__ A, float* __restrict__ cnt_g,
    float* __restrict__ tsum_g) {
    int blk = blockIdx.x;
    int tid = threadIdx.x;
    if (blk < 96) {
        int row    = blk * 8 + (tid >> 5);
        int lane32 = tid & 31;
        const v4f* W4 = (const v4f*)(W + (size_t)row * HID);
        v4f s4 = W4[lane32 * 2] + W4[lane32 * 2 + 1];
        float s = (s4.x + s4.y) + (s4.z + s4.w);
        #pragma unroll
        for (int off = 16; off > 0; off >>= 1) s += __shfl_xor(s, off);
        if (lane32 == 0) colsum[row] = s;
    } else if (blk == 96) {
        __shared__ float red[256];
        red[tid] = bp[tid];
        __syncthreads();
        for (int s = 128; s > 0; s >>= 1) {
            if (tid < s) red[tid] += red[tid + s];
            __syncthreads();
        }
        if (tid == 0) *sumb = red[0];
    } else if (blk == 97) {
        #pragma unroll
        for (int i = 0; i < 4; ++i) {
            cnt_g[i * 256 + tid]  = 0.0f;
            tsum_g[i * 256 + tid] = 0.0f;
        }
    } else {
        // blocks 98..1023 zero A (786432 floats) via grid-stride
        const int nz = 1024 - 98;
        for (size_t idx = (size_t)(blk - 98) * 256 + tid;
             idx < (size_t)1024 * BERT; idx += (size_t)nz * 256)
            A[idx] = 0.0f;
    }
}

// K1: 4096 blocks; block g = (br = g>>2, q4 = g&3) streams the contiguous
// 48 KB slab of sentences [q4*16, q4*16+16) of review br. Wave w handles
// 4 sentences, straight-line 12-load body, per-lane dot partials p[4],
// one batched butterfly after the loads. Rows accumulated unconditionally;
// rows with t == 0 (never, for random input) removed by a rare correction
// pass. Block partials combined in LDS then atomicAdd'ed into A/cnt/tsum.
__global__ __launch_bounds__(256) void k1_reduce(
    const float* __restrict__ inp, const float* __restrict__ colsum,
    const float* __restrict__ sumb, float* __restrict__ A,
    float* __restrict__ cnt_g, float* __restrict__ tsum_g) {
    int g   = blockIdx.x;
    int br  = g >> 2;
    int q4  = g & 3;
    int tid = threadIdx.x;
    int w = tid >> 6, l = tid & 63;

    const v4f* cs4 = (const v4f*)colsum;
    v4f c0 = cs4[l], c1 = cs4[64 + l], c2 = cs4[128 + l];
    float sb = *sumb;

    const v4f* base = (const v4f*)(inp + (size_t)br * NS * BERT);
    int s0 = q4 * 16 + w * 4;

    v4f a0 = {0.f,0.f,0.f,0.f};
    v4f a1 = {0.f,0.f,0.f,0.f};
    v4f a2 = {0.f,0.f,0.f,0.f};
    float p[4];

    #pragma unroll
    for (int i = 0; i < 4; ++i) {
        const v4f* rp = base + (size_t)(s0 + i) * (BERT / 4);
        v4f v0 = rp[l];
        v4f v1 = rp[64 + l];
        v4f v2 = rp[128 + l];
        p[i] = v0.x*c0.x + v0.y*c0.y + v0.z*c0.z + v0.w*c0.w
             + v1.x*c1.x + v1.y*c1.y + v1.z*c1.z + v1.w*c1.w
             + v2.x*c2.x + v2.y*c2.y + v2.z*c2.z + v2.w*c2.w;
        a0 += v0; a1 += v1; a2 += v2;
    }

    // 4 independent butterflies, batched (no serial shfl chain per row).
    #pragma unroll
    for (int off = 32; off > 0; off >>= 1) {
        #pragma unroll
        for (int i = 0; i < 4; ++i) p[i] += __shfl_xor(p[i], off);
    }

    float cnt = 0.f, ts = 0.f;
    bool anyzero = false;
    #pragma unroll
    for (int i = 0; i < 4; ++i) {
        float t = p[i] + sb;
        ts += t;
        cnt += (t != 0.0f) ? 1.0f : 0.0f;
        anyzero |= (t == 0.0f);
    }
    if (anyzero) {   // rare-path exactness: remove rows the mask excludes
        for (int i = 0; i < 4; ++i) {
            if (p[i] + sb == 0.0f) {
                const v4f* rp = base + (size_t)(s0 + i) * (BERT / 4);
                a0 -= rp[l]; a1 -= rp[64 + l]; a2 -= rp[128 + l];
            }
        }
    }

    __shared__ float part[4][BERT];
    __shared__ float cw[4], tw[4];
    float* pw = part[w];
    ((v4f*)pw)[l]       = a0;
    ((v4f*)pw)[64 + l]  = a1;
    ((v4f*)pw)[128 + l] = a2;
    if (l == 0) { cw[w] = cnt; tw[w] = ts; }
    __syncthreads();

    float* Ao = A + (size_t)br * BERT;
    for (int c = tid; c < BERT; c += 256)
        atomicAdd(&Ao[c], (part[0][c] + part[1][c]) + (part[2][c] + part[3][c]));
    if (tid == 0) {
        atomicAdd(&cnt_g[br],  (cw[0] + cw[1]) + (cw[2] + cw[3]));
        atomicAdd(&tsum_g[br], (tw[0] + tw[1]) + (tw[2] + tw[3]));
    }
}

// K2: grid 256 = (b, q) with q = h-quarter of 64 columns. Each block:
//   M[b,:] = sum_r (rm_r / max(cnt_r,1e-9)) * A[b,r,:]   (redundant x4, cheap)
//   p_hn[b,h] = (M.W[:,h] + b_proj[h]*qsum) / rden   for h in [q*64, q*64+64)
//   4-way k-split over d (serial depth 192) for load-latency hiding.
//   Block q==0 additionally emits uf = normalize(user_feats[b]) * user_w.
__global__ __launch_bounds__(256) void k2_gemm(
    const float* __restrict__ A, const float* __restrict__ cnt_g,
    const float* __restrict__ tsum_g, const float* __restrict__ W_proj,
    const float* __restrict__ b_proj, const float* __restrict__ user_feats,
    const float* __restrict__ user_w, float* __restrict__ pb_out) {
    int b   = blockIdx.x >> 2;
    int q   = blockIdx.x & 3;
    int tid = threadIdx.x;

    __shared__ float M[BERT];
    __shared__ float g[NR];
    __shared__ float scal[2];   // [0]=rden, [1]=qsum
    __shared__ float red[256];

    if (tid < NR) {
        float c  = cnt_g[b * NR + tid];
        float t  = tsum_g[b * NR + tid];
        float rm = (t != 0.0f) ? 1.0f : 0.0f;
        float den = fmaxf(c, 1e-9f);
        g[tid]        = rm / den;
        red[tid]      = rm;
        red[NR + tid] = rm * (c / den);
    }
    __syncthreads();
    if (tid == 0) {
        float srm = 0.f, sq = 0.f;
        for (int r = 0; r < NR; ++r) { srm += red[r]; sq += red[NR + r]; }
        scal[0] = fmaxf(srm, 1e-9f);
        scal[1] = sq;
    }
    for (int c = tid; c < BERT; c += 256) {
        float m = 0.f;
        #pragma unroll
        for (int r = 0; r < NR; ++r)
            m += g[r] * A[(size_t)(b * NR + r) * BERT + c];
        M[c] = m;
    }
    __syncthreads();   // M + scal visible

    // k-split dot: thread = (ks = tid>>6) x (hl = tid&63); d-slice of 192
    int hl = tid & 63;
    int ks = tid >> 6;
    int h  = q * 64 + hl;
    {
        const float* Wc = W_proj + h;
        float acc = 0.f;
        int d0 = ks * 192;
        #pragma unroll 16
        for (int j = 0; j < 192; ++j)
            acc += M[d0 + j] * Wc[(size_t)(d0 + j) * HID];
        red[tid] = acc;
    }
    __syncthreads();
    if (tid < 64) {
        float s = (red[tid] + red[64 + tid]) + (red[128 + tid] + red[192 + tid]);
        int hh = q * 64 + tid;
        pb_out[b * PBD + hh] = (s + b_proj[hh] * scal[1]) / scal[0];
    }

    if (q == 0) {
        __syncthreads();
        if (tid == 0) {
            float s = 0.f;
            for (int j = 0; j < NUFD; ++j) {
                float v = user_feats[b * NUFD + j];
                s += v * v;
            }
            red[0] = 1.0f / fmaxf(sqrtf(s), 1e-12f);
        }
        __syncthreads();
        if (tid < NUFD)
            pb_out[b * PBD + HID + tid] =
                user_feats[b * NUFD + tid] * red[0] * user_w[tid];
    }
}

// K3: r_stars[b] = selu(pb[b].W_rff + b_rff);
//     h_n = mean_b pb; p_stars = selu(h_n @ W_pff + b_pff)
__global__ __launch_bounds__(320) void k3_final(
    const float* __restrict__ pb, const float* __restrict__ W_rff,
    const float* __restrict__ b_rff, const float* __restrict__ W_pff,
    const float* __restrict__ b_pff, float* __restrict__ out) {
    __shared__ float hn[PBD];
    int tid = threadIdx.x;
    if (tid < PBD) {
        float s = 0.f;
        #pragma unroll 8
        for (int b = 0; b < NB; ++b) s += pb[b * PBD + tid];
        hn[tid] = s * (1.0f / NB);
    }
    __syncthreads();
    if (tid < NB) {
        int b = tid;
        float acc = 0.f;
        #pragma unroll 12
        for (int j = 0; j < PBD; ++j) acc += pb[b * PBD + j] * W_rff[j];
        out[NLAB + b] = selu_f(acc + b_rff[0]);
    } else if (tid >= 64 && tid < 64 + NLAB) {
        int lab = tid - 64;
        float acc = 0.f;
        #pragma unroll 12
        for (int j = 0; j < PBD; ++j) acc += hn[j] * W_pff[j * NLAB + lab];
        out[lab] = selu_f(acc + b_pff[lab]);
    }
}

extern "C" void kernel_launch(void* const* d_in, const int* in_sizes, int n_in,
                              void* d_out, int out_size, void* d_ws, size_t ws_size,
                              hipStream_t stream) {
    const float* inputs     = (const float*)d_in[0];
    const float* user_feats = (const float*)d_in[1];
    const float* W_proj     = (const float*)d_in[2];
    const float* b_proj     = (const float*)d_in[3];
    const float* W_rff      = (const float*)d_in[4];
    const float* b_rff      = (const float*)d_in[5];
    const float* W_pff      = (const float*)d_in[6];
    const float* b_pff      = (const float*)d_in[7];
    const float* user_w     = (const float*)d_in[8];
    float* out = (float*)d_out;     // [0..8]=p_stars, [9..72]=r_stars
    float* ws  = (float*)d_ws;

    float* A      = ws + WS_A;
    float* colsum = ws + WS_COLSUM;
    float* sumb   = ws + WS_SUMB;
    float* cntg   = ws + WS_CNT;
    float* tsumg  = ws + WS_TSUM;
    float* pb     = ws + WS_PB;

    hipLaunchKernelGGL(k0_colsum, dim3(1024), dim3(256), 0, stream,
                       W_proj, b_proj, colsum, sumb, A, cntg, tsumg);
    hipLaunchKernelGGL(k1_reduce, dim3(NB * NR * 4), dim3(256), 0, stream,
                       inputs, colsum, sumb, A, cntg, tsumg);
    hipLaunchKernelGGL(k2_gemm, dim3(NB * 4), dim3(256), 0, stream,
                       A, cntg, tsumg, W_proj, b_proj, user_feats, user_w, pb);
    hipLaunchKernelGGL(k3_final, dim3(1), dim3(320), 0, stream,
                       pb, W_rff, b_rff, W_pff, b_pff, out);
}

// Round 5
// 302.356 us; speedup vs baseline: 1.0367x; 1.0367x over previous
//
#include <hip/hip_runtime.h>
#include <cmath>

// Problem constants (from reference)
static constexpr int BERT   = 768;
static constexpr int HID    = 256;
static constexpr int NLAB   = 9;
static constexpr int NUFD   = 20;
static constexpr int NB     = 64;
static constexpr int NR     = 16;
static constexpr int NS     = 64;
static constexpr int PBD    = HID + NUFD;  // 276

typedef float v4f __attribute__((ext_vector_type(4)));

// Workspace layout (float offsets). Total ~3.17M floats = 12.7 MB.
static constexpr size_t WS_A4     = 0;          // [1024][4][768] per-wave partial row-sums
static constexpr size_t WS_COLSUM = 3145728;    // [768]
static constexpr size_t WS_SUMB   = 3146496;    // [1] (padded)
static constexpr size_t WS_CNT4   = 3146560;    // [1024][4]
static constexpr size_t WS_TSUM4  = 3150656;    // [1024][4]
static constexpr size_t WS_PB     = 3154752;    // [64][276] p_batch

__device__ __forceinline__ float selu_f(float x) {
    const float alpha = 1.6732632423543772848170429916717f;
    const float scale = 1.0507009873554804934193349852946f;
    return scale * (x > 0.0f ? x : alpha * (expf(x) - 1.0f));
}

// K0: colsum[d] = sum_h W_proj[d][h]; sumb = sum(b_proj)
// 96 blocks x (8 rows x 32 lanes); block 96 reduces b_proj.
__global__ __launch_bounds__(256) void k0_colsum(
    const float* __restrict__ W, const float* __restrict__ bp,
    float* __restrict__ colsum, float* __restrict__ sumb) {
    int blk = blockIdx.x;
    int tid = threadIdx.x;
    if (blk < 96) {
        int row    = blk * 8 + (tid >> 5);
        int lane32 = tid & 31;
        const v4f* W4 = (const v4f*)(W + (size_t)row * HID);
        v4f s4 = W4[lane32 * 2] + W4[lane32 * 2 + 1];
        float s = (s4.x + s4.y) + (s4.z + s4.w);
        #pragma unroll
        for (int off = 16; off > 0; off >>= 1) s += __shfl_xor(s, off);
        if (lane32 == 0) colsum[row] = s;
    } else {
        __shared__ float red[256];
        red[tid] = bp[tid];
        __syncthreads();
        for (int s = 128; s > 0; s >>= 1) {
            if (tid < s) red[tid] += red[tid + s];
            __syncthreads();
        }
        if (tid == 0) *sumb = red[0];
    }
}

// K1: one block per (b,r). Streams 64 rows x 768 f32 (nontemporal).
// Wave w handles sentences [w*16, w*16+16). Rows accumulated
// UNCONDITIONALLY with per-lane dot partials p[16] (batched butterfly after
// the loop); rows with t == 0 (never, for random input) removed by a rare
// correction pass. Each wave writes its 768-f32 partial straight to
// A4[br][w][:] — no LDS, no barriers, no atomics. k2 folds the 4 wave
// partials in (w0+w1)+(w2+w3) order (bit-identical to the R3 kernel).
__global__ __launch_bounds__(256) void k1_reduce(
    const float* __restrict__ inp, const float* __restrict__ colsum,
    const float* __restrict__ sumb, float* __restrict__ A4,
    float* __restrict__ cnt4, float* __restrict__ tsum4) {
    int br  = blockIdx.x;
    int tid = threadIdx.x;
    int w = tid >> 6, l = tid & 63;

    const v4f* cs4 = (const v4f*)colsum;
    v4f c0 = cs4[l], c1 = cs4[64 + l], c2 = cs4[128 + l];
    float sb = *sumb;

    const v4f* base = (const v4f*)(inp + (size_t)br * NS * BERT);
    v4f a0 = {0.f,0.f,0.f,0.f};
    v4f a1 = {0.f,0.f,0.f,0.f};
    v4f a2 = {0.f,0.f,0.f,0.f};
    float p[16];

    #pragma unroll 4
    for (int i = 0; i < 16; ++i) {
        int s = w * 16 + i;
        const v4f* rp = base + (size_t)s * (BERT / 4);
        v4f v0 = __builtin_nontemporal_load(rp + l);
        v4f v1 = __builtin_nontemporal_load(rp + 64 + l);
        v4f v2 = __builtin_nontemporal_load(rp + 128 + l);
        p[i] = v0.x*c0.x + v0.y*c0.y + v0.z*c0.z + v0.w*c0.w
             + v1.x*c1.x + v1.y*c1.y + v1.z*c1.z + v1.w*c1.w
             + v2.x*c2.x + v2.y*c2.y + v2.z*c2.z + v2.w*c2.w;
        a0 += v0; a1 += v1; a2 += v2;
    }

    // Batched butterfly: 16 independent 6-step reductions, fully pipelined.
    #pragma unroll
    for (int off = 32; off > 0; off >>= 1) {
        #pragma unroll
        for (int i = 0; i < 16; ++i) p[i] += __shfl_xor(p[i], off);
    }

    float cnt = 0.f, ts = 0.f;
    bool anyzero = false;
    #pragma unroll
    for (int i = 0; i < 16; ++i) {
        float t = p[i] + sb;
        ts += t;
        cnt += (t != 0.0f) ? 1.0f : 0.0f;
        anyzero |= (t == 0.0f);
    }
    if (anyzero) {   // rare-path exactness: remove rows the mask excludes
        for (int i = 0; i < 16; ++i) {
            if (p[i] + sb == 0.0f) {
                int s = w * 16 + i;
                const v4f* rp = base + (size_t)s * (BERT / 4);
                a0 -= rp[l]; a1 -= rp[64 + l]; a2 -= rp[128 + l];
            }
        }
    }

    // Per-wave direct store: coalesced 16 B/lane, 3 KB per wave.
    v4f* Ao4 = (v4f*)(A4 + ((size_t)br * 4 + w) * BERT);
    Ao4[l]       = a0;
    Ao4[64 + l]  = a1;
    Ao4[128 + l] = a2;
    if (l == 0) {
        cnt4[br * 4 + w]  = cnt;
        tsum4[br * 4 + w] = ts;
    }
}

// K2: grid 256 = (b, q) with q = h-quarter of 64 columns. Each block:
//   fold wave partials (w0+w1)+(w2+w3), then
//   M[b,:] = sum_r (rm_r / max(cnt_r,1e-9)) * A[b,r,:]   (redundant x4, cheap)
//   p_hn[b,h] = (M.W[:,h] + b_proj[h]*qsum) / rden   for h in [q*64, q*64+64)
//   4-way k-split over d (serial depth 192) for load-latency hiding.
//   Block q==0 additionally emits uf = normalize(user_feats[b]) * user_w.
__global__ __launch_bounds__(256) void k2_gemm(
    const float* __restrict__ A4, const float* __restrict__ cnt4,
    const float* __restrict__ tsum4, const float* __restrict__ W_proj,
    const float* __restrict__ b_proj, const float* __restrict__ user_feats,
    const float* __restrict__ user_w, float* __restrict__ pb_out) {
    int b   = blockIdx.x >> 2;
    int q   = blockIdx.x & 3;
    int tid = threadIdx.x;

    __shared__ float M[BERT];
    __shared__ float g[NR];
    __shared__ float scal[2];   // [0]=rden, [1]=qsum
    __shared__ float red[256];

    if (tid < NR) {
        const float* cb = cnt4  + (size_t)(b * NR + tid) * 4;
        const float* tb = tsum4 + (size_t)(b * NR + tid) * 4;
        float c = (cb[0] + cb[1]) + (cb[2] + cb[3]);
        float t = (tb[0] + tb[1]) + (tb[2] + tb[3]);
        float rm = (t != 0.0f) ? 1.0f : 0.0f;
        float den = fmaxf(c, 1e-9f);
        g[tid]        = rm / den;
        red[tid]      = rm;
        red[NR + tid] = rm * (c / den);
    }
    __syncthreads();
    if (tid == 0) {
        float srm = 0.f, sq = 0.f;
        for (int r = 0; r < NR; ++r) { srm += red[r]; sq += red[NR + r]; }
        scal[0] = fmaxf(srm, 1e-9f);
        scal[1] = sq;
    }
    for (int c = tid; c < BERT; c += 256) {
        float m = 0.f;
        #pragma unroll
        for (int r = 0; r < NR; ++r) {
            const float* Ar = A4 + (size_t)(b * NR + r) * 4 * BERT + c;
            float aw = (Ar[0] + Ar[BERT]) + (Ar[2 * BERT] + Ar[3 * BERT]);
            m += g[r] * aw;
        }
        M[c] = m;
    }
    __syncthreads();   // M + scal visible

    // k-split dot: thread = (ks = tid>>6) x (hl = tid&63); d-slice of 192
    int hl = tid & 63;
    int ks = tid >> 6;
    int h  = q * 64 + hl;
    {
        const float* Wc = W_proj + h;
        float acc = 0.f;
        int d0 = ks * 192;
        #pragma unroll 16
        for (int j = 0; j < 192; ++j)
            acc += M[d0 + j] * Wc[(size_t)(d0 + j) * HID];
        red[tid] = acc;
    }
    __syncthreads();
    if (tid < 64) {
        float s = (red[tid] + red[64 + tid]) + (red[128 + tid] + red[192 + tid]);
        int hh = q * 64 + tid;
        pb_out[b * PBD + hh] = (s + b_proj[hh] * scal[1]) / scal[0];
    }

    if (q == 0) {
        __syncthreads();
        if (tid == 0) {
            float s = 0.f;
            for (int j = 0; j < NUFD; ++j) {
                float v = user_feats[b * NUFD + j];
                s += v * v;
            }
            red[0] = 1.0f / fmaxf(sqrtf(s), 1e-12f);
        }
        __syncthreads();
        if (tid < NUFD)
            pb_out[b * PBD + HID + tid] =
                user_feats[b * NUFD + tid] * red[0] * user_w[tid];
    }
}

// K3: r_stars[b] = selu(pb[b].W_rff + b_rff);
//     h_n = mean_b pb; p_stars = selu(h_n @ W_pff + b_pff)
__global__ __launch_bounds__(320) void k3_final(
    const float* __restrict__ pb, const float* __restrict__ W_rff,
    const float* __restrict__ b_rff, const float* __restrict__ W_pff,
    const float* __restrict__ b_pff, float* __restrict__ out) {
    __shared__ float hn[PBD];
    int tid = threadIdx.x;
    if (tid < PBD) {
        float s = 0.f;
        #pragma unroll 8
        for (int b = 0; b < NB; ++b) s += pb[b * PBD + tid];
        hn[tid] = s * (1.0f / NB);
    }
    __syncthreads();
    if (tid < NB) {
        int b = tid;
        float acc = 0.f;
        #pragma unroll 12
        for (int j = 0; j < PBD; ++j) acc += pb[b * PBD + j] * W_rff[j];
        out[NLAB + b] = selu_f(acc + b_rff[0]);
    } else if (tid >= 64 && tid < 64 + NLAB) {
        int lab = tid - 64;
        float acc = 0.f;
        #pragma unroll 12
        for (int j = 0; j < PBD; ++j) acc += hn[j] * W_pff[j * NLAB + lab];
        out[lab] = selu_f(acc + b_pff[lab]);
    }
}

extern "C" void kernel_launch(void* const* d_in, const int* in_sizes, int n_in,
                              void* d_out, int out_size, void* d_ws, size_t ws_size,
                              hipStream_t stream) {
    const float* inputs     = (const float*)d_in[0];
    const float* user_feats = (const float*)d_in[1];
    const float* W_proj     = (const float*)d_in[2];
    const float* b_proj     = (const float*)d_in[3];
    const float* W_rff      = (const float*)d_in[4];
    const float* b_rff      = (const float*)d_in[5];
    const float* W_pff      = (const float*)d_in[6];
    const float* b_pff      = (const float*)d_in[7];
    const float* user_w     = (const float*)d_in[8];
    float* out = (float*)d_out;     // [0..8]=p_stars, [9..72]=r_stars
    float* ws  = (float*)d_ws;

    float* A4     = ws + WS_A4;
    float* colsum = ws + WS_COLSUM;
    float* sumb   = ws + WS_SUMB;
    float* cnt4   = ws + WS_CNT4;
    float* tsum4  = ws + WS_TSUM4;
    float* pb     = ws + WS_PB;

    hipLaunchKernelGGL(k0_colsum, dim3(97), dim3(256), 0, stream,
                       W_proj, b_proj, colsum, sumb);
    hipLaunchKernelGGL(k1_reduce, dim3(NB * NR), dim3(256), 0, stream,
                       inputs, colsum, sumb, A4, cnt4, tsum4);
    hipLaunchKernelGGL(k2_gemm, dim3(NB * 4), dim3(256), 0, stream,
                       A4, cnt4, tsum4, W_proj, b_proj, user_feats, user_w, pb);
    hipLaunchKernelGGL(k3_final, dim3(1), dim3(320), 0, stream,
                       pb, W_rff, b_rff, W_pff, b_pff, out);
}